// Round 1
// baseline (5718.980 us; speedup 1.0000x reference)
//
#include <hip/hip_runtime.h>

// Problem dims
#define TT 512
#define BB 64
#define DXX 128
#define HH 256
#define DZZ 64

typedef __attribute__((ext_vector_type(8))) short short8;
typedef __attribute__((ext_vector_type(4))) float f32x4;

#define DEV static __device__ __forceinline__

DEV unsigned short f2bf(float f){
  unsigned u = __builtin_bit_cast(unsigned, f);
  u += 0x7FFFu + ((u >> 16) & 1u);          // RNE
  return (unsigned short)(u >> 16);
}
DEV float bf2f(unsigned short s){
  unsigned u = ((unsigned)s) << 16;
  return __builtin_bit_cast(float, u);
}
DEV float ftanh(float x){
  float a = fabsf(x);
  float e = __expf(-2.f * a);
  float r = __builtin_amdgcn_rcpf(1.f + e);
  float t = (1.f - e) * r;
  return copysignf(t, x);
}
DEV float fsoftplus(float x){
  float e = __expf(fminf(x, 20.f));
  float s = __logf(1.f + e);
  return (x > 20.f) ? x : s;
}

// ---------------------------------------------------------------------------
// Phase A: xproj for both directions, stored bf16 in MFMA-fragment order:
// xpF[d][s][w][l][32], value v = (mi*4+ni)*4+reg maps to
//   m = (2p+mi)*16 + (l>>4)*4 + reg   (batch row)
//   n = (4q+ni)*16 + (l&15)           (H col),  p=w>>2, q=w&3
// ---------------------------------------------------------------------------
__global__ __launch_bounds__(256, 2) void phaseA(
    const float* __restrict__ X,
    const float* __restrict__ WihF, const float* __restrict__ bihF, const float* __restrict__ bhhF,
    const float* __restrict__ WihB, const float* __restrict__ bihB, const float* __restrict__ bhhB,
    unsigned short* __restrict__ xpF)
{
  const int bid = blockIdx.x;
  const int d = bid >> 9, s = bid & 511;
  const int ts = d ? (TT - 1 - s) : s;
  const float* W  = d ? WihB : WihF;
  const float* bi = d ? bihB : bihF;
  const float* bh = d ? bhhB : bhhF;

  __shared__ __attribute__((aligned(16))) float Xl[64][132];  // padded to break conflicts
  const int tid = threadIdx.x;
  for (int i = tid; i < 2048; i += 256){
    int r = i >> 5, c = (i & 31) * 4;
    *(float4*)&Xl[r][c] = *(const float4*)(X + ((size_t)ts * 64 + r) * DXX + c);
  }
  __syncthreads();

  const int w = tid >> 5, p = w >> 2, q = w & 3;
  const int g = (tid & 31) >> 3;        // = l>>4 for both lane slots
  const int c2 = (tid & 7) * 2;         // = l&15 base

  float acc[8][8];
  #pragma unroll
  for (int a = 0; a < 8; ++a)
    #pragma unroll
    for (int b = 0; b < 8; ++b) acc[a][b] = 0.f;

  for (int kc = 0; kc < DXX; kc += 4){
    float4 xr[8], wr[8];
    #pragma unroll
    for (int bi2 = 0; bi2 < 8; ++bi2){
      int b = (2*p + (bi2 >> 2)) * 16 + g*4 + (bi2 & 3);
      xr[bi2] = *(const float4*)&Xl[b][kc];
    }
    #pragma unroll
    for (int hj = 0; hj < 8; ++hj){
      int h = (4*q + (hj >> 1)) * 16 + c2 + (hj & 1);
      wr[hj] = *(const float4*)(W + (size_t)h * DXX + kc);
    }
    #pragma unroll
    for (int bi2 = 0; bi2 < 8; ++bi2)
      #pragma unroll
      for (int hj = 0; hj < 8; ++hj){
        acc[bi2][hj] += xr[bi2].x * wr[hj].x;
        acc[bi2][hj] += xr[bi2].y * wr[hj].y;
        acc[bi2][hj] += xr[bi2].z * wr[hj].z;
        acc[bi2][hj] += xr[bi2].w * wr[hj].w;
      }
  }

  #pragma unroll
  for (int par = 0; par < 2; ++par){
    int ll = (tid & 31) * 2 + par;
    unsigned short* dst = xpF + ((((size_t)d * TT + s) * 8 + w) * 64 + ll) * 32;
    #pragma unroll
    for (int j = 0; j < 4; ++j){
      unsigned short u[8];
      #pragma unroll
      for (int e = 0; e < 8; ++e){
        int v = 8*j + e, ti = v >> 2, reg = v & 3;
        int mi = ti >> 2, ni = ti & 3;
        int bi2 = mi*4 + reg, hj = ni*2 + par;
        int h = (4*q + ni) * 16 + c2 + par;
        float r = acc[bi2][hj] + bi[h] + bh[h];
        u[e] = f2bf(r);
      }
      uint4 o;
      o.x = u[0] | ((unsigned)u[1] << 16);
      o.y = u[2] | ((unsigned)u[3] << 16);
      o.z = u[4] | ((unsigned)u[5] << 16);
      o.w = u[6] | ((unsigned)u[7] << 16);
      *(uint4*)(dst + 8*j) = o;
    }
  }
}

// ---------------------------------------------------------------------------
// eps permuted to fragment order for the mu-waves of phase C:
// epsF[t][p][qq][l][16], v16 = (mi*2+nj)*4+reg ->
//   m = (2p+mi)*16 + (l>>4)*4+reg, nz = (2qq+nj)*16 + (l&15)
// ---------------------------------------------------------------------------
__global__ void epsPerm(const float* __restrict__ eps, float* __restrict__ epsF){
  const int t = blockIdx.x, tid = threadIdx.x;
  const int p = tid >> 7, qq = (tid >> 6) & 1, l = tid & 63;
  const int l15 = l & 15, l4 = l >> 4;
  float v[16];
  #pragma unroll
  for (int ti2 = 0; ti2 < 4; ++ti2)
    #pragma unroll
    for (int reg = 0; reg < 4; ++reg){
      int mi = ti2 >> 1, nj = ti2 & 1;
      int m  = (2*p + mi) * 16 + l4*4 + reg;
      int nz = (2*qq + nj) * 16 + l15;
      v[ti2*4 + reg] = eps[((size_t)t * 64 + m) * 64 + nz];
    }
  float* dst = epsF + ((((size_t)t * 2 + p) * 2 + qq) * 64 + l) * 16;
  #pragma unroll
  for (int j = 0; j < 4; ++j){
    float4 o; o.x = v[4*j]; o.y = v[4*j+1]; o.z = v[4*j+2]; o.w = v[4*j+3];
    *(float4*)(dst + 4*j) = o;
  }
}

// ---------------------------------------------------------------------------
// Phase B: the two RNN scans. 1 block per direction, 512 threads (8 waves).
// Whh kept in registers as B-fragments; h kept in swizzled LDS (bf16).
// ---------------------------------------------------------------------------
__global__ __launch_bounds__(512, 2) void phaseB(
    const float* __restrict__ WhhF, const float* __restrict__ WhhB,
    const unsigned short* __restrict__ xpF, unsigned short* __restrict__ hF)
{
  const int dir = blockIdx.x;
  const float* Whh = dir ? WhhB : WhhF;
  const int tid = threadIdx.x, w = tid >> 6, l = tid & 63;
  const int p = w >> 2, q = w & 3;
  const int l15 = l & 15, l4 = l >> 4;

  __shared__ __attribute__((aligned(16))) unsigned short hbuf[64 * 256];

  // B-fragments of Whh^T: B[k][n] = Whh[n][k]
  short8 bf[4][8];
  #pragma unroll
  for (int ni = 0; ni < 4; ++ni){
    int n = (4*q + ni) * 16 + l15;
    #pragma unroll
    for (int ks = 0; ks < 8; ++ks){
      int k0 = ks*32 + l4*8;
      const float4* src = (const float4*)(Whh + (size_t)n * HH + k0);
      float4 x0 = src[0], x1 = src[1];
      short8 v;
      v[0]=(short)f2bf(x0.x); v[1]=(short)f2bf(x0.y); v[2]=(short)f2bf(x0.z); v[3]=(short)f2bf(x0.w);
      v[4]=(short)f2bf(x1.x); v[5]=(short)f2bf(x1.y); v[6]=(short)f2bf(x1.z); v[7]=(short)f2bf(x1.w);
      bf[ni][ks] = v;
    }
  }
  for (int i = tid; i < 64*256/2; i += 512) ((unsigned*)hbuf)[i] = 0u;   // h_0 = 0

  const int rowA0 = (2*p + 0) * 16 + l15;
  const int rowA1 = (2*p + 1) * 16 + l15;

  const unsigned short* xpD = xpF + (size_t)dir * TT * 8 * 64 * 32;
  unsigned short* hD = hF + (size_t)dir * TT * 8 * 64 * 32;

  uint4 xq[4];
  {
    const uint4* src = (const uint4*)(xpD + ((size_t)0 * 8 + w) * 64 * 32 + l * 32);
    xq[0]=src[0]; xq[1]=src[1]; xq[2]=src[2]; xq[3]=src[3];
  }
  __syncthreads();

  for (int s = 0; s < TT; ++s){
    // acc <- xp (C-fragment order)
    f32x4 acc[8];
    #pragma unroll
    for (int j = 0; j < 4; ++j){
      uint4 t = xq[j];
      acc[2*j+0][0]=bf2f(t.x & 0xffff); acc[2*j+0][1]=bf2f(t.x >> 16);
      acc[2*j+0][2]=bf2f(t.y & 0xffff); acc[2*j+0][3]=bf2f(t.y >> 16);
      acc[2*j+1][0]=bf2f(t.z & 0xffff); acc[2*j+1][1]=bf2f(t.z >> 16);
      acc[2*j+1][2]=bf2f(t.w & 0xffff); acc[2*j+1][3]=bf2f(t.w >> 16);
    }
    // prefetch next step's xp
    {
      int sn = (s + 1 < TT) ? s + 1 : s;
      const uint4* src = (const uint4*)(xpD + ((size_t)sn * 8 + w) * 64 * 32 + l * 32);
      xq[0]=src[0]; xq[1]=src[1]; xq[2]=src[2]; xq[3]=src[3];
    }
    // h_{s-1} @ Whh^T
    #pragma unroll
    for (int ks = 0; ks < 8; ++ks){
      int kc = ks*32 + l4*8;
      int i0 = (rowA0*256 + kc) ^ ((rowA0 & 7) << 3);
      int i1 = (rowA1*256 + kc) ^ ((rowA1 & 7) << 3);
      short8 a0 = *(const short8*)(hbuf + i0);
      short8 a1 = *(const short8*)(hbuf + i1);
      #pragma unroll
      for (int ni = 0; ni < 4; ++ni){
        acc[ni]   = __builtin_amdgcn_mfma_f32_16x16x32_bf16(a0, bf[ni][ks], acc[ni],   0, 0, 0);
        acc[4+ni] = __builtin_amdgcn_mfma_f32_16x16x32_bf16(a1, bf[ni][ks], acc[4+ni], 0, 0, 0);
      }
    }
    __syncthreads();   // all reads of h_{s-1} done

    const int tg = dir ? (TT - 1 - s) : s;
    unsigned short* dst = hD + ((size_t)tg * 8 + w) * 64 * 32 + l * 32;
    #pragma unroll
    for (int j = 0; j < 4; ++j){
      unsigned short u[8];
      #pragma unroll
      for (int e = 0; e < 8; ++e){
        int v = 8*j + e, ti = v >> 2, reg = v & 3;
        int mi = ti >> 2, ni = ti & 3;
        int m = (2*p + mi) * 16 + l4*4 + reg;
        int n = (4*q + ni) * 16 + l15;
        float hv = ftanh(acc[ti][reg]);
        unsigned short uu = f2bf(hv);
        hbuf[(m*256 + n) ^ ((m & 7) << 3)] = uu;
        u[e] = uu;
      }
      uint4 o;
      o.x = u[0] | ((unsigned)u[1] << 16);
      o.y = u[2] | ((unsigned)u[3] << 16);
      o.z = u[4] | ((unsigned)u[5] << 16);
      o.w = u[6] | ((unsigned)u[7] << 16);
      *(uint4*)(dst + 8*j) = o;
    }
    __syncthreads();   // h_s fully written
  }
}

// ---------------------------------------------------------------------------
// Phase C: latent scan. 1 block, 512 threads (8 waves).
// ---------------------------------------------------------------------------
__global__ __launch_bounds__(512, 2) void phaseC(
    const float* __restrict__ Wt,  const float* __restrict__ bt,
    const float* __restrict__ Wmu, const float* __restrict__ bmu,
    const float* __restrict__ Wsig,const float* __restrict__ bsig,
    const float* __restrict__ epsF, const unsigned short* __restrict__ hF,
    float* __restrict__ out)
{
  const int tid = threadIdx.x, w = tid >> 6, l = tid & 63;
  const int p = w >> 2, q = w & 3;
  const int l15 = l & 15, l4 = l >> 4;

  __shared__ __attribute__((aligned(16))) unsigned short zbuf[64 * 64];
  __shared__ __attribute__((aligned(16))) unsigned short hbuf[64 * 256];
  __shared__ float sbuf[64 * 68];

  // Wt fragments (transition): B[k=DZ][n=H] = Wt[n][k]
  short8 btf[4][2]; float btr[4];
  #pragma unroll
  for (int ni = 0; ni < 4; ++ni){
    int n = (4*q + ni) * 16 + l15;
    btr[ni] = bt[n];
    #pragma unroll
    for (int ks = 0; ks < 2; ++ks){
      int k0 = ks*32 + l4*8;
      const float4* src = (const float4*)(Wt + (size_t)n * DZZ + k0);
      float4 x0 = src[0], x1 = src[1];
      short8 v;
      v[0]=(short)f2bf(x0.x); v[1]=(short)f2bf(x0.y); v[2]=(short)f2bf(x0.z); v[3]=(short)f2bf(x0.w);
      v[4]=(short)f2bf(x1.x); v[5]=(short)f2bf(x1.y); v[6]=(short)f2bf(x1.z); v[7]=(short)f2bf(x1.w);
      btf[ni][ks] = v;
    }
  }
  // [Wmu; Wsig] fragments: combined N=128
  short8 bmsf[2][8]; float bms[2];
  #pragma unroll
  for (int nj = 0; nj < 2; ++nj){
    int n128 = (2*q + nj) * 16 + l15;
    const float* Wrow; float bb;
    if (n128 < 64){ Wrow = Wmu  + (size_t)n128 * HH;        bb = bmu[n128]; }
    else          { Wrow = Wsig + (size_t)(n128 - 64) * HH; bb = bsig[n128 - 64]; }
    bms[nj] = bb;
    #pragma unroll
    for (int ks = 0; ks < 8; ++ks){
      int k0 = ks*32 + l4*8;
      const float4* src = (const float4*)(Wrow + k0);
      float4 x0 = src[0], x1 = src[1];
      short8 v;
      v[0]=(short)f2bf(x0.x); v[1]=(short)f2bf(x0.y); v[2]=(short)f2bf(x0.z); v[3]=(short)f2bf(x0.w);
      v[4]=(short)f2bf(x1.x); v[5]=(short)f2bf(x1.y); v[6]=(short)f2bf(x1.z); v[7]=(short)f2bf(x1.w);
      bmsf[nj][ks] = v;
    }
  }

  for (int i = tid; i < 64*64/2; i += 512) ((unsigned*)zbuf)[i] = 0u;   // z_0 = 0

  const int rowA0 = 2*p*16 + l15, rowA1 = rowA0 + 16;
  const size_t TBZ = (size_t)TT * 64 * 64;

  uint4 hlq[4], hrq[4]; float ef[16];
  {
    const uint4* sl = (const uint4*)(hF + (((size_t)0 * TT + 0) * 8 + w) * 64 * 32 + l * 32);
    const uint4* sr = (const uint4*)(hF + (((size_t)1 * TT + 0) * 8 + w) * 64 * 32 + l * 32);
    hlq[0]=sl[0]; hlq[1]=sl[1]; hlq[2]=sl[2]; hlq[3]=sl[3];
    hrq[0]=sr[0]; hrq[1]=sr[1]; hrq[2]=sr[2]; hrq[3]=sr[3];
    if (q < 2){
      const float4* se = (const float4*)(epsF + ((((size_t)0 * 2 + p) * 2 + q) * 64 + l) * 16);
      #pragma unroll
      for (int j = 0; j < 4; ++j){ float4 t = se[j]; ef[4*j]=t.x; ef[4*j+1]=t.y; ef[4*j+2]=t.z; ef[4*j+3]=t.w; }
    }
  }
  __syncthreads();

  for (int t = 0; t < TT; ++t){
    // 1) tmp_pre = z_prev @ Wt^T + bt
    f32x4 at[8];
    #pragma unroll
    for (int ti = 0; ti < 8; ++ti){
      float b = btr[ti & 3];
      at[ti][0]=b; at[ti][1]=b; at[ti][2]=b; at[ti][3]=b;
    }
    #pragma unroll
    for (int ks = 0; ks < 2; ++ks){
      int kc = ks*32 + l4*8;
      short8 a0 = *(const short8*)(zbuf + ((rowA0*64 + kc) ^ ((rowA0 & 7) << 3)));
      short8 a1 = *(const short8*)(zbuf + ((rowA1*64 + kc) ^ ((rowA1 & 7) << 3)));
      #pragma unroll
      for (int ni = 0; ni < 4; ++ni){
        at[ni]   = __builtin_amdgcn_mfma_f32_16x16x32_bf16(a0, btf[ni][ks], at[ni],   0, 0, 0);
        at[4+ni] = __builtin_amdgcn_mfma_f32_16x16x32_bf16(a1, btf[ni][ks], at[4+ni], 0, 0, 0);
      }
    }
    // 2) h_t = (tanh(at) + hl + hr)/3 -> swizzled LDS
    #pragma unroll
    for (int j = 0; j < 4; ++j){
      uint4 tl = hlq[j], tr = hrq[j];
      unsigned lw[4] = {tl.x, tl.y, tl.z, tl.w};
      unsigned rw[4] = {tr.x, tr.y, tr.z, tr.w};
      #pragma unroll
      for (int e = 0; e < 8; ++e){
        int v = 8*j + e, ti = v >> 2, reg = v & 3;
        int mi = ti >> 2, ni = ti & 3;
        unsigned lu = lw[e >> 1], ru = rw[e >> 1];
        float hlv = bf2f((e & 1) ? (unsigned short)(lu >> 16) : (unsigned short)(lu & 0xffff));
        float hrv = bf2f((e & 1) ? (unsigned short)(ru >> 16) : (unsigned short)(ru & 0xffff));
        float hv = (ftanh(at[ti][reg]) + hlv + hrv) * (1.f / 3.f);
        int m = (2*p + mi) * 16 + l4*4 + reg;
        int n = (4*q + ni) * 16 + l15;
        hbuf[(m*256 + n) ^ ((m & 7) << 3)] = f2bf(hv);
      }
    }
    // prefetch next hl/hr
    {
      int tn = (t + 1 < TT) ? t + 1 : t;
      const uint4* sl = (const uint4*)(hF + (((size_t)0 * TT + tn) * 8 + w) * 64 * 32 + l * 32);
      const uint4* sr = (const uint4*)(hF + (((size_t)1 * TT + tn) * 8 + w) * 64 * 32 + l * 32);
      hlq[0]=sl[0]; hlq[1]=sl[1]; hlq[2]=sl[2]; hlq[3]=sl[3];
      hrq[0]=sr[0]; hrq[1]=sr[1]; hrq[2]=sr[2]; hrq[3]=sr[3];
    }
    __syncthreads();

    // 3) [mu|sig]_pre = h_t @ [Wmu;Wsig]^T + b
    f32x4 am[4];
    #pragma unroll
    for (int ti2 = 0; ti2 < 4; ++ti2){
      float b = bms[ti2 & 1];
      am[ti2][0]=b; am[ti2][1]=b; am[ti2][2]=b; am[ti2][3]=b;
    }
    #pragma unroll
    for (int ks = 0; ks < 8; ++ks){
      int kc = ks*32 + l4*8;
      short8 a0 = *(const short8*)(hbuf + ((rowA0*256 + kc) ^ ((rowA0 & 7) << 3)));
      short8 a1 = *(const short8*)(hbuf + ((rowA1*256 + kc) ^ ((rowA1 & 7) << 3)));
      #pragma unroll
      for (int nj = 0; nj < 2; ++nj){
        am[nj]   = __builtin_amdgcn_mfma_f32_16x16x32_bf16(a0, bmsf[nj][ks], am[nj],   0, 0, 0);
        am[2+nj] = __builtin_amdgcn_mfma_f32_16x16x32_bf16(a1, bmsf[nj][ks], am[2+nj], 0, 0, 0);
      }
    }
    // 4) epilogue
    if (q >= 2){
      #pragma unroll
      for (int ti2 = 0; ti2 < 4; ++ti2)
        #pragma unroll
        for (int reg = 0; reg < 4; ++reg){
          int mi = ti2 >> 1, nj = ti2 & 1;
          int m  = (2*p + mi) * 16 + l4*4 + reg;
          int nz = (2*(q - 2) + nj) * 16 + l15;
          float sp = fsoftplus(am[ti2][reg]);
          sbuf[m*68 + nz] = sp;
          out[2*TBZ + ((size_t)t * 64 + m) * 64 + nz] = sp;
        }
    } else {
      #pragma unroll
      for (int ti2 = 0; ti2 < 4; ++ti2)
        #pragma unroll
        for (int reg = 0; reg < 4; ++reg){
          int mi = ti2 >> 1, nj = ti2 & 1;
          int m  = (2*p + mi) * 16 + l4*4 + reg;
          int nz = (2*q + nj) * 16 + l15;
          out[TBZ + ((size_t)t * 64 + m) * 64 + nz] = am[ti2][reg];
        }
    }
    __syncthreads();   // sbuf (std) visible
    if (q < 2){
      #pragma unroll
      for (int ti2 = 0; ti2 < 4; ++ti2)
        #pragma unroll
        for (int reg = 0; reg < 4; ++reg){
          int mi = ti2 >> 1, nj = ti2 & 1;
          int m  = (2*p + mi) * 16 + l4*4 + reg;
          int nz = (2*q + nj) * 16 + l15;
          float sd = sbuf[m*68 + nz];
          float zv = am[ti2][reg] + sd * ef[ti2*4 + reg];
          out[((size_t)t * 64 + m) * 64 + nz] = zv;
          zbuf[(m*64 + nz) ^ ((m & 7) << 3)] = f2bf(zv);
        }
      // prefetch next eps
      int tn = (t + 1 < TT) ? t + 1 : t;
      const float4* se = (const float4*)(epsF + ((((size_t)tn * 2 + p) * 2 + q) * 64 + l) * 16);
      #pragma unroll
      for (int j = 0; j < 4; ++j){ float4 tv = se[j]; ef[4*j]=tv.x; ef[4*j+1]=tv.y; ef[4*j+2]=tv.z; ef[4*j+3]=tv.w; }
    }
    __syncthreads();   // zbuf ready for next step
  }
}

// ---------------------------------------------------------------------------
extern "C" void kernel_launch(void* const* d_in, const int* in_sizes, int n_in,
                              void* d_out, int out_size, void* d_ws, size_t ws_size,
                              hipStream_t stream)
{
  const float* X      = (const float*)d_in[0];
  const float* Wih_f  = (const float*)d_in[1];
  const float* Whh_f  = (const float*)d_in[2];
  const float* bih_f  = (const float*)d_in[3];
  const float* bhh_f  = (const float*)d_in[4];
  const float* Wih_b  = (const float*)d_in[5];
  const float* Whh_b  = (const float*)d_in[6];
  const float* bih_b  = (const float*)d_in[7];
  const float* bhh_b  = (const float*)d_in[8];
  const float* Wt     = (const float*)d_in[9];
  const float* bt     = (const float*)d_in[10];
  const float* Wmu    = (const float*)d_in[11];
  const float* bmu    = (const float*)d_in[12];
  const float* Wsig   = (const float*)d_in[13];
  const float* bsig   = (const float*)d_in[14];
  const float* eps    = (const float*)d_in[15];

  // Workspace layout (needs ~76 MB):
  //   xpF : ushort[2][T][8][64][32]   (32 MB)
  //   hF  : ushort[2][T][8][64][32]   (32 MB)
  //   epsF: float [T][2][2][64][16]   ( 8 MB)
  unsigned short* xpF = (unsigned short*)d_ws;
  unsigned short* hF  = xpF + (size_t)2 * TT * 8 * 64 * 32;
  float* epsF = (float*)(hF + (size_t)2 * TT * 8 * 64 * 32);

  phaseA<<<dim3(1024), dim3(256), 0, stream>>>(X, Wih_f, bih_f, bhh_f, Wih_b, bih_b, bhh_b, xpF);
  epsPerm<<<dim3(512), dim3(256), 0, stream>>>(eps, epsF);
  phaseB<<<dim3(2), dim3(512), 0, stream>>>(Whh_f, Whh_b, xpF, hF);
  phaseC<<<dim3(1), dim3(512), 0, stream>>>(Wt, bt, Wmu, bmu, Wsig, bsig, epsF, hF, (float*)d_out);
}

// Round 2
// 1213.902 us; speedup vs baseline: 4.7112x; 4.7112x over previous
//
#include <hip/hip_runtime.h>

// Problem dims
#define TT 512
#define BB 64
#define DXX 128
#define HH 256
#define DZZ 64

typedef __attribute__((ext_vector_type(8))) short short8;
typedef __attribute__((ext_vector_type(4))) float f32x4;

#define DEV static __device__ __forceinline__

DEV unsigned short f2bf(float f){
  unsigned u = __builtin_bit_cast(unsigned, f);
  u += 0x7FFFu + ((u >> 16) & 1u);          // RNE
  return (unsigned short)(u >> 16);
}
DEV float bf2f(unsigned short s){
  unsigned u = ((unsigned)s) << 16;
  return __builtin_bit_cast(float, u);
}
DEV float ftanh(float x){
  float a = fabsf(x);
  float e = __expf(-2.f * a);
  float r = __builtin_amdgcn_rcpf(1.f + e);
  float t = (1.f - e) * r;
  return copysignf(t, x);
}
DEV float fsoftplus(float x){
  float e = __expf(fminf(x, 20.f));
  float s = __logf(1.f + e);
  return (x > 20.f) ? x : s;
}
DEV short8 pack8(const float* p){   // 8 consecutive f32 -> bf16x8
  short8 v;
  #pragma unroll
  for (int i = 0; i < 8; ++i) v[i] = (short)f2bf(p[i]);
  return v;
}

// Fragment conventions (verified round 1, mfma_f32_16x16x32_bf16):
//   A-frag: lane l holds A[row=l&15][k=(l>>4)*8+e]
//   B-frag: lane l holds B[k=(l>>4)*8+e][col=l&15]
//   C-frag: value reg r at (row=(l>>4)*4+r, col=l&15)
// Packed 16-value lane payload (words w8=0..7): ni=w8>>1, rb=(w8&1)*2,
//   lo half = value (ni, rb), hi half = value (ni, rb+1);
//   value (ni,reg): m = (l>>4)*4+reg (within 16-row tile), n = 64q+16ni+(l&15)

// ---------------------------------------------------------------------------
// Phase A: xp = X @ Wih^T + bih + bhh for both directions, MFMA, stored bf16
// packed per (d, s, bq, q, l): xpF[d][s][bq][q][l][16]
// ---------------------------------------------------------------------------
__global__ __launch_bounds__(256, 2) void phaseA(
    const float* __restrict__ X,
    const float* __restrict__ WihF, const float* __restrict__ bihF, const float* __restrict__ bhhF,
    const float* __restrict__ WihB, const float* __restrict__ bihB, const float* __restrict__ bhhB,
    unsigned short* __restrict__ xpF)
{
  const int bid = blockIdx.x;
  const int d = bid >> 9, s = bid & 511;
  const int ts = d ? (TT - 1 - s) : s;
  const float* W  = d ? WihB : WihF;
  const float* bi = d ? bihB : bihF;
  const float* bh = d ? bhhB : bhhF;

  const int tid = threadIdx.x, q = tid >> 6, l = tid & 63;
  const int l15 = l & 15, l4 = l >> 4;

  // B-frags of Wih^T for this wave's 64 cols
  short8 bfv[4][4];
  float bias[4];
  #pragma unroll
  for (int ni = 0; ni < 4; ++ni){
    int n = 64*q + 16*ni + l15;
    bias[ni] = bi[n] + bh[n];
    #pragma unroll
    for (int ks = 0; ks < 4; ++ks)
      bfv[ni][ks] = pack8(W + (size_t)n * DXX + ks*32 + l4*8);
  }

  #pragma unroll
  for (int bq = 0; bq < 4; ++bq){
    const float* xr = X + ((size_t)ts * 64 + 16*bq + l15) * DXX;
    short8 af[4];
    #pragma unroll
    for (int ks = 0; ks < 4; ++ks) af[ks] = pack8(xr + ks*32 + l4*8);

    f32x4 acc[4];
    #pragma unroll
    for (int ni = 0; ni < 4; ++ni){
      acc[ni][0]=bias[ni]; acc[ni][1]=bias[ni]; acc[ni][2]=bias[ni]; acc[ni][3]=bias[ni];
    }
    #pragma unroll
    for (int ks = 0; ks < 4; ++ks)
      #pragma unroll
      for (int ni = 0; ni < 4; ++ni)
        acc[ni] = __builtin_amdgcn_mfma_f32_16x16x32_bf16(af[ks], bfv[ni][ks], acc[ni], 0, 0, 0);

    unsigned wd[8];
    #pragma unroll
    for (int w8 = 0; w8 < 8; ++w8){
      int ni = w8 >> 1, rb = (w8 & 1) * 2;
      wd[w8] = (unsigned)f2bf(acc[ni][rb]) | ((unsigned)f2bf(acc[ni][rb+1]) << 16);
    }
    unsigned short* dst = xpF + ((((size_t)d*TT + s)*4 + bq)*4 + q)*1024 + (size_t)l*16;
    uint4 o0 = {wd[0], wd[1], wd[2], wd[3]};
    uint4 o1 = {wd[4], wd[5], wd[6], wd[7]};
    ((uint4*)dst)[0] = o0;
    ((uint4*)dst)[1] = o1;
  }
}

// ---------------------------------------------------------------------------
// eps permuted: epsF[t][bq][q][l] = float4 { eps[t][m][nz] for reg=0..3 }
//   m = 16bq + (l>>4)*4 + reg, nz = 16q + (l&15)
// ---------------------------------------------------------------------------
__global__ void epsPerm(const float* __restrict__ eps, float* __restrict__ epsF){
  const int t = blockIdx.x, tid = threadIdx.x;
  const int q = tid >> 6, l = tid & 63;
  const int l15 = l & 15, l4 = l >> 4;
  const int nz = 16*q + l15;
  #pragma unroll
  for (int bq = 0; bq < 4; ++bq){
    float4 o;
    int m0 = 16*bq + l4*4;
    o.x = eps[((size_t)t*64 + m0 + 0)*64 + nz];
    o.y = eps[((size_t)t*64 + m0 + 1)*64 + nz];
    o.z = eps[((size_t)t*64 + m0 + 2)*64 + nz];
    o.w = eps[((size_t)t*64 + m0 + 3)*64 + nz];
    *(float4*)(epsF + ((((size_t)t*4 + bq)*4 + q)*64 + l)*4) = o;
  }
}

// ---------------------------------------------------------------------------
// Phase B: the two RNN scans split over batch. 8 blocks (dir, bq) x 256 thr.
// Whh in registers (B-frags); h in double-buffered swizzled LDS (1 barrier).
// ---------------------------------------------------------------------------
__global__ __launch_bounds__(256, 1) void phaseB(
    const float* __restrict__ WhhF, const float* __restrict__ WhhB,
    const unsigned short* __restrict__ xpF, unsigned short* __restrict__ hF)
{
  const int dir = blockIdx.x >> 2, bq = blockIdx.x & 3;
  const float* Whh = dir ? WhhB : WhhF;
  const int tid = threadIdx.x, q = tid >> 6, l = tid & 63;
  const int l15 = l & 15, l4 = l >> 4;

  __shared__ __attribute__((aligned(16))) unsigned short hbuf[2][16 * 256];

  short8 bf[4][8];
  #pragma unroll
  for (int ni = 0; ni < 4; ++ni){
    int n = 64*q + 16*ni + l15;
    #pragma unroll
    for (int ks = 0; ks < 8; ++ks)
      bf[ni][ks] = pack8(Whh + (size_t)n * HH + ks*32 + l4*8);
  }
  for (int i = tid; i < 16*256/2; i += 256) ((unsigned*)hbuf[0])[i] = 0u;  // h_0 = 0

  const size_t strideS = 16384;   // ushorts per timestep
  const size_t laneOff = (size_t)bq*4096 + (size_t)q*1024 + (size_t)l*16;
  const unsigned short* xpP = xpF + (size_t)dir*TT*strideS + laneOff;
  unsigned short* hD = hF + (size_t)dir*TT*strideS + laneOff;

  uint4 xq0, xq1;
  { const uint4* src = (const uint4*)xpP; xq0 = src[0]; xq1 = src[1]; }

  unsigned pw[8];
  size_t prevOff = 0;
  __syncthreads();

  for (int s = 0; s < TT; ++s){
    // deferred global store of h_{s-1} (retires during this step's compute)
    if (s > 0){
      uint4 o0 = {pw[0], pw[1], pw[2], pw[3]};
      uint4 o1 = {pw[4], pw[5], pw[6], pw[7]};
      *(uint4*)(hD + prevOff)     = o0;
      *(uint4*)(hD + prevOff + 8) = o1;
    }
    const int rp = s & 1, wc = rp ^ 1;

    f32x4 acc[4];
    {
      unsigned w8v[8] = {xq0.x, xq0.y, xq0.z, xq0.w, xq1.x, xq1.y, xq1.z, xq1.w};
      #pragma unroll
      for (int w8 = 0; w8 < 8; ++w8){
        int ni = w8 >> 1, rb = (w8 & 1) * 2;
        acc[ni][rb]   = bf2f((unsigned short)(w8v[w8] & 0xffff));
        acc[ni][rb+1] = bf2f((unsigned short)(w8v[w8] >> 16));
      }
    }
    // prefetch next xp
    if (s + 1 < TT){
      const uint4* src = (const uint4*)(xpP + (size_t)(s+1) * strideS);
      xq0 = src[0]; xq1 = src[1];
    }
    // h_{s-1} @ Whh^T
    #pragma unroll
    for (int ks = 0; ks < 8; ++ks){
      int idx = (l15*256 + ks*32 + l4*8) ^ ((l15 & 7) << 3);
      short8 a = *(const short8*)(hbuf[rp] + idx);
      #pragma unroll
      for (int ni = 0; ni < 4; ++ni)
        acc[ni] = __builtin_amdgcn_mfma_f32_16x16x32_bf16(a, bf[ni][ks], acc[ni], 0, 0, 0);
    }
    // tanh -> LDS (other buffer) + pack for deferred global store
    #pragma unroll
    for (int ni = 0; ni < 4; ++ni){
      int n = 64*q + 16*ni + l15;
      #pragma unroll
      for (int rb = 0; rb < 4; rb += 2){
        unsigned u0 = f2bf(ftanh(acc[ni][rb]));
        unsigned u1 = f2bf(ftanh(acc[ni][rb+1]));
        int m0 = l4*4 + rb, m1 = m0 + 1;
        hbuf[wc][(m0*256 + n) ^ ((m0 & 7) << 3)] = (unsigned short)u0;
        hbuf[wc][(m1*256 + n) ^ ((m1 & 7) << 3)] = (unsigned short)u1;
        pw[ni*2 + (rb >> 1)] = u0 | (u1 << 16);
      }
    }
    prevOff = (size_t)(dir ? (TT - 1 - s) : s) * strideS;
    __syncthreads();   // h_s visible; also covers read-buffer reuse next step
  }
  {
    uint4 o0 = {pw[0], pw[1], pw[2], pw[3]};
    uint4 o1 = {pw[4], pw[5], pw[6], pw[7]};
    *(uint4*)(hD + prevOff)     = o0;
    *(uint4*)(hD + prevOff + 8) = o1;
  }
}

// ---------------------------------------------------------------------------
// Phase C: latent scan split over batch. 4 blocks (bq) x 256 thr, 2 barriers.
// Wave q owns mu cols [16q,16q+16) AND sig cols for the same nz -> z fully
// in-register (no cross-wave std exchange).
// ---------------------------------------------------------------------------
__global__ __launch_bounds__(256, 1) void phaseC(
    const float* __restrict__ Wt,  const float* __restrict__ bt,
    const float* __restrict__ Wmu, const float* __restrict__ bmu,
    const float* __restrict__ Wsig,const float* __restrict__ bsig,
    const float* __restrict__ epsF, const unsigned short* __restrict__ hF,
    float* __restrict__ out)
{
  const int bq = blockIdx.x;
  const int tid = threadIdx.x, q = tid >> 6, l = tid & 63;
  const int l15 = l & 15, l4 = l >> 4;

  __shared__ __attribute__((aligned(16))) unsigned short zbuf[16 * 64];
  __shared__ __attribute__((aligned(16))) unsigned short hbuf[16 * 256];

  // transition weights: B[k=DZ][n=H] = Wt[n][k]
  short8 btf[4][2]; float btr[4];
  #pragma unroll
  for (int ni = 0; ni < 4; ++ni){
    int n = 64*q + 16*ni + l15;
    btr[ni] = bt[n];
    #pragma unroll
    for (int ks = 0; ks < 2; ++ks)
      btf[ni][ks] = pack8(Wt + (size_t)n * DZZ + ks*32 + l4*8);
  }
  // mu/sig weights: same output cols nz = 16q + l15 for both
  short8 bmsf[2][8]; float bms[2];
  {
    int r = 16*q + l15;
    bms[0] = bmu[r]; bms[1] = bsig[r];
    #pragma unroll
    for (int ks = 0; ks < 8; ++ks){
      bmsf[0][ks] = pack8(Wmu  + (size_t)r * HH + ks*32 + l4*8);
      bmsf[1][ks] = pack8(Wsig + (size_t)r * HH + ks*32 + l4*8);
    }
  }
  for (int i = tid; i < 16*64/2; i += 256) ((unsigned*)zbuf)[i] = 0u;  // z_0 = 0

  const size_t strideS = 16384;
  const size_t laneOff = (size_t)bq*4096 + (size_t)q*1024 + (size_t)l*16;
  const unsigned short* hLp = hF + laneOff;
  const unsigned short* hRp = hLp + (size_t)TT * strideS;
  const float* eP = epsF + (((size_t)bq*4 + q)*64 + l)*4;

  unsigned hlw[8], hrw[8];
  float efv[4];
  {
    const uint4* sl = (const uint4*)hLp;
    const uint4* sr = (const uint4*)hRp;
    uint4 a = sl[0], b = sl[1], c = sr[0], d2 = sr[1];
    hlw[0]=a.x; hlw[1]=a.y; hlw[2]=a.z; hlw[3]=a.w; hlw[4]=b.x; hlw[5]=b.y; hlw[6]=b.z; hlw[7]=b.w;
    hrw[0]=c.x; hrw[1]=c.y; hrw[2]=c.z; hrw[3]=c.w; hrw[4]=d2.x; hrw[5]=d2.y; hrw[6]=d2.z; hrw[7]=d2.w;
    float4 e4 = *(const float4*)eP;
    efv[0]=e4.x; efv[1]=e4.y; efv[2]=e4.z; efv[3]=e4.w;
  }
  const size_t TBZ = (size_t)TT * 64 * 64;
  const int nz = 16*q + l15;
  float dmu[4], dsp[4], dz[4];

  __syncthreads();

  for (int t = 0; t < TT; ++t){
    // deferred stores for t-1 (retire during this step)
    if (t > 0){
      #pragma unroll
      for (int reg = 0; reg < 4; ++reg){
        int M = 16*bq + l4*4 + reg;
        size_t ob = ((size_t)(t-1)*64 + M)*64 + nz;
        out[ob]         = dz[reg];
        out[TBZ + ob]   = dmu[reg];
        out[2*TBZ + ob] = dsp[reg];
      }
    }
    // 1) transition: z_prev @ Wt^T + bt
    f32x4 at[4];
    #pragma unroll
    for (int ni = 0; ni < 4; ++ni){
      at[ni][0]=btr[ni]; at[ni][1]=btr[ni]; at[ni][2]=btr[ni]; at[ni][3]=btr[ni];
    }
    #pragma unroll
    for (int ks = 0; ks < 2; ++ks){
      int idx = (l15*64 + ks*32 + l4*8) ^ ((l15 & 7) << 3);
      short8 a = *(const short8*)(zbuf + idx);
      #pragma unroll
      for (int ni = 0; ni < 4; ++ni)
        at[ni] = __builtin_amdgcn_mfma_f32_16x16x32_bf16(a, btf[ni][ks], at[ni], 0, 0, 0);
    }
    // 2) h_t = (tanh + hl + hr)/3 -> swizzled LDS
    #pragma unroll
    for (int ni = 0; ni < 4; ++ni){
      int n = 64*q + 16*ni + l15;
      #pragma unroll
      for (int rb = 0; rb < 4; rb += 2){
        unsigned lw = hlw[ni*2 + (rb >> 1)], rw = hrw[ni*2 + (rb >> 1)];
        float h0 = (ftanh(at[ni][rb])   + bf2f((unsigned short)(lw & 0xffff)) + bf2f((unsigned short)(rw & 0xffff))) * (1.f/3.f);
        float h1 = (ftanh(at[ni][rb+1]) + bf2f((unsigned short)(lw >> 16))    + bf2f((unsigned short)(rw >> 16)))    * (1.f/3.f);
        int m0 = l4*4 + rb, m1 = m0 + 1;
        hbuf[(m0*256 + n) ^ ((m0 & 7) << 3)] = f2bf(h0);
        hbuf[(m1*256 + n) ^ ((m1 & 7) << 3)] = f2bf(h1);
      }
    }
    // prefetch next hl/hr
    if (t + 1 < TT){
      const uint4* sl = (const uint4*)(hLp + (size_t)(t+1)*strideS);
      const uint4* sr = (const uint4*)(hRp + (size_t)(t+1)*strideS);
      uint4 a = sl[0], b = sl[1], c = sr[0], d2 = sr[1];
      hlw[0]=a.x; hlw[1]=a.y; hlw[2]=a.z; hlw[3]=a.w; hlw[4]=b.x; hlw[5]=b.y; hlw[6]=b.z; hlw[7]=b.w;
      hrw[0]=c.x; hrw[1]=c.y; hrw[2]=c.z; hrw[3]=c.w; hrw[4]=d2.x; hrw[5]=d2.y; hrw[6]=d2.z; hrw[7]=d2.w;
    }
    __syncthreads();   // h_t visible

    // 3) mu/sig for this wave's 16 cols (nj=0 mu, nj=1 sig)
    f32x4 am[2];
    am[0][0]=bms[0]; am[0][1]=bms[0]; am[0][2]=bms[0]; am[0][3]=bms[0];
    am[1][0]=bms[1]; am[1][1]=bms[1]; am[1][2]=bms[1]; am[1][3]=bms[1];
    #pragma unroll
    for (int ks = 0; ks < 8; ++ks){
      int idx = (l15*256 + ks*32 + l4*8) ^ ((l15 & 7) << 3);
      short8 a = *(const short8*)(hbuf + idx);
      am[0] = __builtin_amdgcn_mfma_f32_16x16x32_bf16(a, bmsf[0][ks], am[0], 0, 0, 0);
      am[1] = __builtin_amdgcn_mfma_f32_16x16x32_bf16(a, bmsf[1][ks], am[1], 0, 0, 0);
    }
    // 4) reparameterization fully in-register; z -> swizzled LDS
    #pragma unroll
    for (int reg = 0; reg < 4; ++reg){
      float mu = am[0][reg];
      float sp = fsoftplus(am[1][reg]);
      float zv = mu + sp * efv[reg];
      int m = l4*4 + reg;
      zbuf[(m*64 + nz) ^ ((m & 7) << 3)] = f2bf(zv);
      dmu[reg] = mu; dsp[reg] = sp; dz[reg] = zv;
    }
    // prefetch next eps
    if (t + 1 < TT){
      float4 e4 = *(const float4*)(eP + (size_t)(t+1)*4096);
      efv[0]=e4.x; efv[1]=e4.y; efv[2]=e4.z; efv[3]=e4.w;
    }
    __syncthreads();   // z_t visible for next transition
  }
  {
    #pragma unroll
    for (int reg = 0; reg < 4; ++reg){
      int M = 16*bq + l4*4 + reg;
      size_t ob = ((size_t)(TT-1)*64 + M)*64 + nz;
      out[ob]         = dz[reg];
      out[TBZ + ob]   = dmu[reg];
      out[2*TBZ + ob] = dsp[reg];
    }
  }
}

// ---------------------------------------------------------------------------
extern "C" void kernel_launch(void* const* d_in, const int* in_sizes, int n_in,
                              void* d_out, int out_size, void* d_ws, size_t ws_size,
                              hipStream_t stream)
{
  const float* X      = (const float*)d_in[0];
  const float* Wih_f  = (const float*)d_in[1];
  const float* Whh_f  = (const float*)d_in[2];
  const float* bih_f  = (const float*)d_in[3];
  const float* bhh_f  = (const float*)d_in[4];
  const float* Wih_b  = (const float*)d_in[5];
  const float* Whh_b  = (const float*)d_in[6];
  const float* bih_b  = (const float*)d_in[7];
  const float* bhh_b  = (const float*)d_in[8];
  const float* Wt     = (const float*)d_in[9];
  const float* bt     = (const float*)d_in[10];
  const float* Wmu    = (const float*)d_in[11];
  const float* bmu    = (const float*)d_in[12];
  const float* Wsig   = (const float*)d_in[13];
  const float* bsig   = (const float*)d_in[14];
  const float* eps    = (const float*)d_in[15];

  // Workspace: xpF (33.5MB) + hF (33.5MB) + epsF (8.4MB)
  unsigned short* xpF = (unsigned short*)d_ws;
  unsigned short* hF  = xpF + (size_t)2 * TT * 16384;
  float* epsF = (float*)(hF + (size_t)2 * TT * 16384);

  phaseA<<<dim3(1024), dim3(256), 0, stream>>>(X, Wih_f, bih_f, bhh_f, Wih_b, bih_b, bhh_b, xpF);
  epsPerm<<<dim3(512), dim3(256), 0, stream>>>(eps, epsF);
  phaseB<<<dim3(8), dim3(256), 0, stream>>>(Whh_f, Whh_b, xpF, hF);
  phaseC<<<dim3(4), dim3(256), 0, stream>>>(Wt, bt, Wmu, bmu, Wsig, bsig, epsF, hF, (float*)d_out);
}